// Round 2
// baseline (2062.288 us; speedup 1.0000x reference)
//
#include <hip/hip_runtime.h>

#define NSTATES 16

static __device__ __forceinline__ float4 ld4(const float* p) {
    return *reinterpret_cast<const float4*>(p);
}
static __device__ __forceinline__ void st4(float* p, float4 v) {
    *reinterpret_cast<float4*>(p) = v;
}

// ---------------------------------------------------------------------------
// K1: priors = softmax(features @ W); also init beliefs, log_priors, log_b.
// 16 lanes per node, one state per lane. W staged in LDS (8 KB).
// ---------------------------------------------------------------------------
__global__ void priors_kernel(const float* __restrict__ feat,
                              const float* __restrict__ W,
                              float* __restrict__ priors_out,
                              float* __restrict__ beliefs,
                              float* __restrict__ log_priors,
                              float* __restrict__ log_b,
                              int n_nodes)
{
    __shared__ float Wl[128 * NSTATES];
    for (int i = threadIdx.x; i < 128 * NSTATES; i += blockDim.x)
        Wl[i] = W[i];
    __syncthreads();

    long long gid = (long long)blockIdx.x * blockDim.x + threadIdx.x;
    int node = (int)(gid >> 4);
    if (node >= n_nodes) return;
    int s = (int)(gid & 15);

    const float4* f4 = reinterpret_cast<const float4*>(feat + (size_t)node * 128);
    float acc = 0.f;
#pragma unroll
    for (int i = 0; i < 32; ++i) {
        float4 f = f4[i];
        acc = fmaf(f.x, Wl[(i * 4 + 0) * NSTATES + s], acc);
        acc = fmaf(f.y, Wl[(i * 4 + 1) * NSTATES + s], acc);
        acc = fmaf(f.z, Wl[(i * 4 + 2) * NSTATES + s], acc);
        acc = fmaf(f.w, Wl[(i * 4 + 3) * NSTATES + s], acc);
    }
    // softmax across the 16-lane group
    float mx = acc;
#pragma unroll
    for (int off = 1; off < 16; off <<= 1)
        mx = fmaxf(mx, __shfl_xor(mx, off, 64));
    float ex = expf(acc - mx);
    float sm = ex;
#pragma unroll
    for (int off = 1; off < 16; off <<= 1)
        sm += __shfl_xor(sm, off, 64);
    float p = ex / sm;

    size_t idx = (size_t)node * NSTATES + s;
    priors_out[idx] = p;
    beliefs[idx]    = p;
    float lp = logf(fmaxf(p, 1e-10f));
    log_priors[idx] = lp;
    log_b[idx]      = lp;
}

// ---------------------------------------------------------------------------
// KA: per undirected edge pair (p, rev[p]): message update for both directions
// + fused atomic scatter of log(messages) into log_b.
// rev is an involution with rev[p] >= n_pairs for p < n_pairs, so each pair's
// two message rows are exclusively owned by one 4-lane group (no races, no
// double buffer). 4 lanes per pair, float4 per lane.
// potential = ones + (e-1)*I  =>  (t@pot)[j] = s + (e-1)*t[j],  rowsum=(15+e)*s
// ---------------------------------------------------------------------------
template <bool FIRST, bool LAST>
__global__ void edge_kernel(const float* __restrict__ beliefs,
                            float* __restrict__ messages,
                            const int* __restrict__ src,
                            const int* __restrict__ dst,
                            const int* __restrict__ rev,
                            float* __restrict__ log_b,
                            int n_pairs)
{
    long long gid = (long long)blockIdx.x * blockDim.x + threadIdx.x;
    int p = (int)(gid >> 2);
    if (p >= n_pairs) return;
    int sub = (int)(gid & 3);

    int u  = src[p];
    int v  = dst[p];
    int re = rev[p];

    const float EM1  = 1.7182818284590452354f;   // e - 1
    const float SUMF = 17.718281828459045235f;   // 15 + e

    float4 bu = ld4(beliefs + (size_t)u * NSTATES + sub * 4);
    float4 bv = ld4(beliefs + (size_t)v * NSTATES + sub * 4);

    float4 tf, tr;
    if (FIRST) {
        // messages are exactly 1/16 -> t = 16*b (exact)
        tf = make_float4(bu.x * 16.f, bu.y * 16.f, bu.z * 16.f, bu.w * 16.f);
        tr = make_float4(bv.x * 16.f, bv.y * 16.f, bv.z * 16.f, bv.w * 16.f);
    } else {
        float4 mf = ld4(messages + (size_t)p  * NSTATES + sub * 4);
        float4 mr = ld4(messages + (size_t)re * NSTATES + sub * 4);
        tf = make_float4(bu.x / mr.x, bu.y / mr.y, bu.z / mr.z, bu.w / mr.w);
        tr = make_float4(bv.x / mf.x, bv.y / mf.y, bv.z / mf.z, bv.w / mf.w);
    }

    float sf = (tf.x + tf.y) + (tf.z + tf.w);
    float sr = (tr.x + tr.y) + (tr.z + tr.w);
    sf += __shfl_xor(sf, 1, 64);
    sf += __shfl_xor(sf, 2, 64);
    sr += __shfl_xor(sr, 1, 64);
    sr += __shfl_xor(sr, 2, 64);

    float invf = 1.0f / (SUMF * sf);
    float invr = 1.0f / (SUMF * sr);

    float4 nf, nr;
    nf.x = fmaf(EM1, tf.x, sf) * invf;
    nf.y = fmaf(EM1, tf.y, sf) * invf;
    nf.z = fmaf(EM1, tf.z, sf) * invf;
    nf.w = fmaf(EM1, tf.w, sf) * invf;
    nr.x = fmaf(EM1, tr.x, sr) * invr;
    nr.y = fmaf(EM1, tr.y, sr) * invr;
    nr.z = fmaf(EM1, tr.z, sr) * invr;
    nr.w = fmaf(EM1, tr.w, sr) * invr;

    if (!LAST) {
        st4(messages + (size_t)p  * NSTATES + sub * 4, nf);
        st4(messages + (size_t)re * NSTATES + sub * 4, nr);
    }

    // scatter log(messages): fwd edge p has dst v; rev edge has dst u
    float* lv = log_b + (size_t)v * NSTATES + sub * 4;
    float* lu = log_b + (size_t)u * NSTATES + sub * 4;
    atomicAdd(lv + 0, logf(fmaxf(nf.x, 1e-10f)));
    atomicAdd(lv + 1, logf(fmaxf(nf.y, 1e-10f)));
    atomicAdd(lv + 2, logf(fmaxf(nf.z, 1e-10f)));
    atomicAdd(lv + 3, logf(fmaxf(nf.w, 1e-10f)));
    atomicAdd(lu + 0, logf(fmaxf(nr.x, 1e-10f)));
    atomicAdd(lu + 1, logf(fmaxf(nr.y, 1e-10f)));
    atomicAdd(lu + 2, logf(fmaxf(nr.z, 1e-10f)));
    atomicAdd(lu + 3, logf(fmaxf(nr.w, 1e-10f)));
}

// ---------------------------------------------------------------------------
// KB: beliefs = softmax(log_b); on non-last iters also reset log_b=log_priors.
// 4 lanes per node, float4 per lane.
// ---------------------------------------------------------------------------
template <bool LAST>
__global__ void belief_kernel(float* __restrict__ log_b,
                              const float* __restrict__ log_priors,
                              float* __restrict__ beliefs,
                              float* __restrict__ out_beliefs,
                              int n_nodes)
{
    long long gid = (long long)blockIdx.x * blockDim.x + threadIdx.x;
    int node = (int)(gid >> 2);
    if (node >= n_nodes) return;
    int sub = (int)(gid & 3);

    size_t base = (size_t)node * NSTATES + sub * 4;
    float4 lb = ld4(log_b + base);
    float mx = fmaxf(fmaxf(lb.x, lb.y), fmaxf(lb.z, lb.w));
    mx = fmaxf(mx, __shfl_xor(mx, 1, 64));
    mx = fmaxf(mx, __shfl_xor(mx, 2, 64));
    float4 e;
    e.x = expf(lb.x - mx);
    e.y = expf(lb.y - mx);
    e.z = expf(lb.z - mx);
    e.w = expf(lb.w - mx);
    float sm = (e.x + e.y) + (e.z + e.w);
    sm += __shfl_xor(sm, 1, 64);
    sm += __shfl_xor(sm, 2, 64);
    float inv = 1.0f / sm;
    float4 b = make_float4(e.x * inv, e.y * inv, e.z * inv, e.w * inv);

    if (LAST) {
        st4(out_beliefs + base, b);
    } else {
        st4(beliefs + base, b);
        st4(log_b + base, ld4(log_priors + base));  // reset for next scatter
    }
}

// ---------------------------------------------------------------------------
extern "C" void kernel_launch(void* const* d_in, const int* in_sizes, int n_in,
                              void* d_out, int out_size, void* d_ws, size_t ws_size,
                              hipStream_t stream)
{
    const float* feat = (const float*)d_in[0];
    const float* W    = (const float*)d_in[1];
    const int*   src  = (const int*)d_in[2];
    const int*   dst  = (const int*)d_in[3];
    const int*   rev  = (const int*)d_in[4];

    int n_nodes = in_sizes[0] / 128;
    int n_dir   = in_sizes[2];
    int n_pairs = n_dir / 2;

    float* out         = (float*)d_out;
    float* priors_out  = out;                               // [n_nodes*16]
    float* beliefs_out = out + (size_t)n_nodes * NSTATES;   // [n_nodes*16]

    float* ws         = (float*)d_ws;
    float* beliefs    = ws;                                       // n_nodes*16
    float* log_priors = beliefs    + (size_t)n_nodes * NSTATES;   // n_nodes*16
    float* log_b      = log_priors + (size_t)n_nodes * NSTATES;   // n_nodes*16
    float* messages   = log_b      + (size_t)n_nodes * NSTATES;   // n_dir*16

    const int BLK = 256;
    int grid1 = (n_nodes * NSTATES + BLK - 1) / BLK;        // 16 lanes/node
    int gridE = (n_pairs * 4 + BLK - 1) / BLK;              // 4 lanes/pair
    int gridN = (n_nodes * 4 + BLK - 1) / BLK;              // 4 lanes/node

    priors_kernel<<<grid1, BLK, 0, stream>>>(feat, W, priors_out, beliefs,
                                             log_priors, log_b, n_nodes);

    // iter 0: messages uniform (no read), write messages
    edge_kernel<true, false><<<gridE, BLK, 0, stream>>>(beliefs, messages, src,
                                                        dst, rev, log_b, n_pairs);
    belief_kernel<false><<<gridN, BLK, 0, stream>>>(log_b, log_priors, beliefs,
                                                    nullptr, n_nodes);
    // iter 1: read + write messages
    edge_kernel<false, false><<<gridE, BLK, 0, stream>>>(beliefs, messages, src,
                                                         dst, rev, log_b, n_pairs);
    belief_kernel<false><<<gridN, BLK, 0, stream>>>(log_b, log_priors, beliefs,
                                                    nullptr, n_nodes);
    // iter 2 (last): read messages, no write
    edge_kernel<false, true><<<gridE, BLK, 0, stream>>>(beliefs, messages, src,
                                                        dst, rev, log_b, n_pairs);
    belief_kernel<true><<<gridN, BLK, 0, stream>>>(log_b, log_priors, beliefs,
                                                   beliefs_out, n_nodes);
}

// Round 3
// 1148.474 us; speedup vs baseline: 1.7957x; 1.7957x over previous
//
#include <hip/hip_runtime.h>

#define NSTATES 16

static __device__ __forceinline__ float4 ld4(const float* p) {
    return *reinterpret_cast<const float4*>(p);
}
static __device__ __forceinline__ void st4(float* p, float4 v) {
    *reinterpret_cast<float4*>(p) = v;
}

// ---------------------------------------------------------------------------
// K1: priors = softmax(features @ W); also init beliefs + log_priors.
// 16 lanes per node, one state per lane. W staged in LDS (8 KB).
// ---------------------------------------------------------------------------
__global__ void priors_kernel(const float* __restrict__ feat,
                              const float* __restrict__ W,
                              float* __restrict__ priors_out,
                              float* __restrict__ beliefs,
                              float* __restrict__ log_priors,
                              int n_nodes)
{
    __shared__ float Wl[128 * NSTATES];
    for (int i = threadIdx.x; i < 128 * NSTATES; i += blockDim.x)
        Wl[i] = W[i];
    __syncthreads();

    long long gid = (long long)blockIdx.x * blockDim.x + threadIdx.x;
    int node = (int)(gid >> 4);
    if (node >= n_nodes) return;
    int s = (int)(gid & 15);

    const float4* f4 = reinterpret_cast<const float4*>(feat + (size_t)node * 128);
    float acc = 0.f;
#pragma unroll
    for (int i = 0; i < 32; ++i) {
        float4 f = f4[i];
        acc = fmaf(f.x, Wl[(i * 4 + 0) * NSTATES + s], acc);
        acc = fmaf(f.y, Wl[(i * 4 + 1) * NSTATES + s], acc);
        acc = fmaf(f.z, Wl[(i * 4 + 2) * NSTATES + s], acc);
        acc = fmaf(f.w, Wl[(i * 4 + 3) * NSTATES + s], acc);
    }
    float mx = acc;
#pragma unroll
    for (int off = 1; off < 16; off <<= 1)
        mx = fmaxf(mx, __shfl_xor(mx, off, 64));
    float ex = expf(acc - mx);
    float sm = ex;
#pragma unroll
    for (int off = 1; off < 16; off <<= 1)
        sm += __shfl_xor(sm, off, 64);
    float p = ex / sm;

    size_t idx = (size_t)node * NSTATES + s;
    priors_out[idx] = p;
    beliefs[idx]    = p;
    log_priors[idx] = logf(fmaxf(p, 1e-10f));
}

// ---------------------------------------------------------------------------
// CSR build: histogram over dst, exclusive scan, fill slot->edge_id.
// Once per call; int atomics only.
// ---------------------------------------------------------------------------
__global__ void hist_kernel(const int* __restrict__ dst, int* __restrict__ cnt,
                            int n)
{
    int i = blockIdx.x * blockDim.x + threadIdx.x;
    if (i < n) atomicAdd(&cnt[dst[i]], 1);
}

// single workgroup, 1024 threads, wave-scan based exclusive prefix sum
__global__ void scan_kernel(const int* __restrict__ cnt,
                            int* __restrict__ row_ptr, int n)
{
    __shared__ int wsum[16];
    __shared__ int woff[16];
    __shared__ int running_s;
    if (threadIdx.x == 0) running_s = 0;
    __syncthreads();
    int lane = threadIdx.x & 63;
    int wid  = threadIdx.x >> 6;
    for (int base = 0; base < n; base += (int)blockDim.x) {
        int i = base + threadIdx.x;
        int x = (i < n) ? cnt[i] : 0;
        int v = x;
#pragma unroll
        for (int off = 1; off < 64; off <<= 1) {
            int t = __shfl_up(v, off, 64);
            if (lane >= off) v += t;
        }
        if (lane == 63) wsum[wid] = v;
        __syncthreads();
        if (threadIdx.x == 0) {
            int acc = running_s;
            for (int w = 0; w < 16; ++w) { woff[w] = acc; acc += wsum[w]; }
            running_s = acc;
        }
        __syncthreads();
        if (i < n) row_ptr[i] = woff[wid] + (v - x);   // exclusive prefix
        __syncthreads();   // protect wsum/woff/running_s for next chunk
    }
    if (threadIdx.x == 0) row_ptr[n] = running_s;
}

__global__ void fill_kernel(const int* __restrict__ dst,
                            const int* __restrict__ row_ptr,
                            int* __restrict__ fill,
                            int* __restrict__ edge_id, int n)
{
    int i = blockIdx.x * blockDim.x + threadIdx.x;
    if (i < n) {
        int d = dst[i];
        int slot = row_ptr[d] + atomicAdd(&fill[d], 1);
        edge_id[slot] = i;
    }
}

// ---------------------------------------------------------------------------
// Edge kernel: per undirected pair (p, rev[p]) update both directed messages.
// Pure streaming on messages (edge-id order), no atomics, no scatter.
// potential = ones + (e-1)*I  =>  (t@pot)[j] = s + (e-1)*t[j], rowsum=(15+e)*s
// ---------------------------------------------------------------------------
template <bool FIRST>
__global__ void edge_kernel(const float* __restrict__ beliefs,
                            float* __restrict__ messages,
                            const int* __restrict__ src,
                            const int* __restrict__ dst,
                            const int* __restrict__ rev,
                            int n_pairs)
{
    long long gid = (long long)blockIdx.x * blockDim.x + threadIdx.x;
    int p = (int)(gid >> 2);
    if (p >= n_pairs) return;
    int sub = (int)(gid & 3);

    int u  = src[p];
    int v  = dst[p];
    int re = rev[p];

    const float EM1  = 1.7182818284590452354f;   // e - 1
    const float SUMF = 17.718281828459045235f;   // 15 + e

    float4 bu = ld4(beliefs + (size_t)u * NSTATES + sub * 4);
    float4 bv = ld4(beliefs + (size_t)v * NSTATES + sub * 4);

    float4 tf, tr;
    if (FIRST) {
        // messages are exactly 1/16 -> t = 16*b (exact)
        tf = make_float4(bu.x * 16.f, bu.y * 16.f, bu.z * 16.f, bu.w * 16.f);
        tr = make_float4(bv.x * 16.f, bv.y * 16.f, bv.z * 16.f, bv.w * 16.f);
    } else {
        float4 mf = ld4(messages + (size_t)p  * NSTATES + sub * 4);
        float4 mr = ld4(messages + (size_t)re * NSTATES + sub * 4);
        tf = make_float4(bu.x / mr.x, bu.y / mr.y, bu.z / mr.z, bu.w / mr.w);
        tr = make_float4(bv.x / mf.x, bv.y / mf.y, bv.z / mf.z, bv.w / mf.w);
    }

    float sf = (tf.x + tf.y) + (tf.z + tf.w);
    float sr = (tr.x + tr.y) + (tr.z + tr.w);
    sf += __shfl_xor(sf, 1, 64);
    sf += __shfl_xor(sf, 2, 64);
    sr += __shfl_xor(sr, 1, 64);
    sr += __shfl_xor(sr, 2, 64);

    float invf = 1.0f / (SUMF * sf);
    float invr = 1.0f / (SUMF * sr);

    float4 nf, nr;
    nf.x = fmaf(EM1, tf.x, sf) * invf;
    nf.y = fmaf(EM1, tf.y, sf) * invf;
    nf.z = fmaf(EM1, tf.z, sf) * invf;
    nf.w = fmaf(EM1, tf.w, sf) * invf;
    nr.x = fmaf(EM1, tr.x, sr) * invr;
    nr.y = fmaf(EM1, tr.y, sr) * invr;
    nr.z = fmaf(EM1, tr.z, sr) * invr;
    nr.w = fmaf(EM1, tr.w, sr) * invr;

    st4(messages + (size_t)p  * NSTATES + sub * 4, nf);
    st4(messages + (size_t)re * NSTATES + sub * 4, nr);
}

// ---------------------------------------------------------------------------
// Belief kernel: one wave per node. Gather incoming messages via CSR,
// sum logs in-register, softmax, write beliefs (ws) or final output.
// Lanes: 4 row-groups x 16 states.
// ---------------------------------------------------------------------------
template <bool LAST>
__global__ void belief_kernel(const float* __restrict__ messages,
                              const int* __restrict__ edge_id,
                              const int* __restrict__ row_ptr,
                              const float* __restrict__ log_priors,
                              float* __restrict__ beliefs,
                              float* __restrict__ out_beliefs,
                              int n_nodes)
{
    long long gid = (long long)blockIdx.x * blockDim.x + threadIdx.x;
    int node = (int)(gid >> 6);
    if (node >= n_nodes) return;
    int lane = threadIdx.x & 63;
    int s    = lane & 15;
    int rg   = lane >> 4;   // 0..3

    int start = row_ptr[node];
    int end   = row_ptr[node + 1];

    float acc = 0.f;
    for (int r = start + rg; r < end; r += 4) {
        int e = edge_id[r];
        float m = messages[(size_t)e * NSTATES + s];
        acc += logf(fmaxf(m, 1e-10f));
    }
    // reduce across the 4 row-groups (lanes with equal s)
    acc += __shfl_xor(acc, 16, 64);
    acc += __shfl_xor(acc, 32, 64);

    float lb = acc + log_priors[(size_t)node * NSTATES + s];

    float mx = lb;
#pragma unroll
    for (int off = 1; off < 16; off <<= 1)
        mx = fmaxf(mx, __shfl_xor(mx, off, 64));
    float e_ = expf(lb - mx);
    float sm = e_;
#pragma unroll
    for (int off = 1; off < 16; off <<= 1)
        sm += __shfl_xor(sm, off, 64);
    float b = e_ / sm;

    if (rg == 0) {
        size_t idx = (size_t)node * NSTATES + s;
        if (LAST) out_beliefs[idx] = b;
        else      beliefs[idx]     = b;
    }
}

// ---------------------------------------------------------------------------
extern "C" void kernel_launch(void* const* d_in, const int* in_sizes, int n_in,
                              void* d_out, int out_size, void* d_ws, size_t ws_size,
                              hipStream_t stream)
{
    const float* feat = (const float*)d_in[0];
    const float* W    = (const float*)d_in[1];
    const int*   src  = (const int*)d_in[2];
    const int*   dst  = (const int*)d_in[3];
    const int*   rev  = (const int*)d_in[4];

    int n_nodes = in_sizes[0] / 128;
    int n_dir   = in_sizes[2];
    int n_pairs = n_dir / 2;

    float* out         = (float*)d_out;
    float* priors_out  = out;                               // [n_nodes*16]
    float* beliefs_out = out + (size_t)n_nodes * NSTATES;   // [n_nodes*16]

    size_t NN16 = (size_t)n_nodes * NSTATES;
    size_t ME   = (size_t)n_dir * NSTATES;

    float* ws         = (float*)d_ws;
    float* beliefs    = ws;                         // NN16 f32
    float* log_priors = beliefs + NN16;             // NN16 f32
    float* messages   = log_priors + NN16;          // ME f32 (edge-id order)
    int*   edge_id    = (int*)(messages + ME);      // n_dir int (CSR slots)
    int*   row_ptr    = edge_id + n_dir;            // n_nodes+1 int
    int*   cnt        = row_ptr + n_nodes + 1;      // n_nodes int
    int*   fill       = cnt + n_nodes;              // n_nodes int

    const int BLK = 256;
    int grid1 = (int)((NN16 + BLK - 1) / BLK);                 // 16 lanes/node
    int gridE = (int)(((size_t)n_pairs * 4 + BLK - 1) / BLK);  // 4 lanes/pair
    int gridH = (n_dir + BLK - 1) / BLK;                       // 1 lane/edge
    int gridB = (int)(((size_t)n_nodes * 64 + BLK - 1) / BLK); // wave/node

    // --- CSR build (int atomics only, once per call) ---
    hipMemsetAsync(cnt, 0, 2 * (size_t)n_nodes * sizeof(int), stream); // cnt+fill
    hist_kernel<<<gridH, BLK, 0, stream>>>(dst, cnt, n_dir);
    scan_kernel<<<1, 1024, 0, stream>>>(cnt, row_ptr, n_nodes);
    fill_kernel<<<gridH, BLK, 0, stream>>>(dst, row_ptr, fill, edge_id, n_dir);

    // --- priors / init ---
    priors_kernel<<<grid1, BLK, 0, stream>>>(feat, W, priors_out, beliefs,
                                             log_priors, n_nodes);

    // --- 3 diffusion iterations ---
    edge_kernel<true><<<gridE, BLK, 0, stream>>>(beliefs, messages, src, dst,
                                                 rev, n_pairs);
    belief_kernel<false><<<gridB, BLK, 0, stream>>>(messages, edge_id, row_ptr,
                                                    log_priors, beliefs,
                                                    nullptr, n_nodes);

    edge_kernel<false><<<gridE, BLK, 0, stream>>>(beliefs, messages, src, dst,
                                                  rev, n_pairs);
    belief_kernel<false><<<gridB, BLK, 0, stream>>>(messages, edge_id, row_ptr,
                                                    log_priors, beliefs,
                                                    nullptr, n_nodes);

    edge_kernel<false><<<gridE, BLK, 0, stream>>>(beliefs, messages, src, dst,
                                                  rev, n_pairs);
    belief_kernel<true><<<gridB, BLK, 0, stream>>>(messages, edge_id, row_ptr,
                                                   log_priors, beliefs,
                                                   beliefs_out, n_nodes);
}

// Round 5
// 870.125 us; speedup vs baseline: 2.3701x; 1.3199x over previous
//
#include <hip/hip_runtime.h>

#define NSTATES 16

static __device__ __forceinline__ float4 ld4(const float* p) {
    return *reinterpret_cast<const float4*>(p);
}
static __device__ __forceinline__ void st4(float* p, float4 v) {
    *reinterpret_cast<float4*>(p) = v;
}

// ---------------------------------------------------------------------------
// Priors: softmax(features @ W); init working beliefs + log_priors.
// 16 lanes per node, one state per lane. W staged in LDS (8 KB).
// ---------------------------------------------------------------------------
__global__ void priors_kernel(const float* __restrict__ feat,
                              const float* __restrict__ W,
                              float* __restrict__ priors_out,
                              float* __restrict__ beliefs,
                              float* __restrict__ log_priors,
                              int n_nodes)
{
    __shared__ float Wl[128 * NSTATES];
    for (int i = threadIdx.x; i < 128 * NSTATES; i += blockDim.x)
        Wl[i] = W[i];
    __syncthreads();

    long long gid = (long long)blockIdx.x * blockDim.x + threadIdx.x;
    int node = (int)(gid >> 4);
    if (node >= n_nodes) return;
    int s = (int)(gid & 15);

    const float4* f4 = reinterpret_cast<const float4*>(feat + (size_t)node * 128);
    float acc = 0.f;
#pragma unroll
    for (int i = 0; i < 32; ++i) {
        float4 f = f4[i];
        acc = fmaf(f.x, Wl[(i * 4 + 0) * NSTATES + s], acc);
        acc = fmaf(f.y, Wl[(i * 4 + 1) * NSTATES + s], acc);
        acc = fmaf(f.z, Wl[(i * 4 + 2) * NSTATES + s], acc);
        acc = fmaf(f.w, Wl[(i * 4 + 3) * NSTATES + s], acc);
    }
    float mx = acc;
#pragma unroll
    for (int off = 1; off < 16; off <<= 1)
        mx = fmaxf(mx, __shfl_xor(mx, off, 64));
    float ex = expf(acc - mx);
    float sm = ex;
#pragma unroll
    for (int off = 1; off < 16; off <<= 1)
        sm += __shfl_xor(sm, off, 64);
    float p = ex / sm;

    size_t idx = (size_t)node * NSTATES + s;
    priors_out[idx] = p;
    beliefs[idx]    = p;
    log_priors[idx] = logf(fmaxf(p, 1e-10f));
}

// ---------------------------------------------------------------------------
// CSR build, pass 1: per-edge within-dst rank + degree histogram (one atomic
// pass). r[i] written sequentially; any rank order is valid (sum commutes,
// slot mapping stays a bijection used consistently for read & write).
// ---------------------------------------------------------------------------
__global__ void rank_kernel(const int* __restrict__ dst, int* __restrict__ cnt,
                            int* __restrict__ r, int n)
{
    int i = blockIdx.x * blockDim.x + threadIdx.x;
    if (i < n) r[i] = atomicAdd(&cnt[dst[i]], 1);
}

// ---------------------------------------------------------------------------
// Hierarchical exclusive scan of cnt[0..n) -> row_ptr. 1024 elements/block.
// ---------------------------------------------------------------------------
__global__ void scan1_kernel(const int* __restrict__ cnt,
                             int* __restrict__ row_ptr,
                             int* __restrict__ bsum, int n)
{
    int base = blockIdx.x * 1024;
    int t = threadIdx.x;            // 0..255
    int i0 = base + t * 4;
    int a0 = (i0 + 0 < n) ? cnt[i0 + 0] : 0;
    int a1 = (i0 + 1 < n) ? cnt[i0 + 1] : 0;
    int a2 = (i0 + 2 < n) ? cnt[i0 + 2] : 0;
    int a3 = (i0 + 3 < n) ? cnt[i0 + 3] : 0;
    int sl = a0 + a1 + a2 + a3;

    int lane = t & 63, wid = t >> 6;
    int v = sl;
#pragma unroll
    for (int off = 1; off < 64; off <<= 1) {
        int tv = __shfl_up(v, off, 64);
        if (lane >= off) v += tv;
    }
    __shared__ int wtot[4], woff[4];
    if (lane == 63) wtot[wid] = v;
    __syncthreads();
    if (t == 0) {
        int a = 0;
        for (int w = 0; w < 4; ++w) { woff[w] = a; a += wtot[w]; }
        bsum[blockIdx.x] = a;
    }
    __syncthreads();
    int excl = woff[wid] + (v - sl);
    if (i0 + 0 < n) row_ptr[i0 + 0] = excl;
    if (i0 + 1 < n) row_ptr[i0 + 1] = excl + a0;
    if (i0 + 2 < n) row_ptr[i0 + 2] = excl + a0 + a1;
    if (i0 + 3 < n) row_ptr[i0 + 3] = excl + a0 + a1 + a2;
}

// single wave scans the ~98 block sums in place (exclusive)
__global__ void scan2_kernel(int* __restrict__ bsum, int nb)
{
    __shared__ int run;
    int lane = threadIdx.x;
    if (lane == 0) run = 0;
    __syncthreads();
    for (int b = 0; b < nb; b += 64) {
        int i = b + lane;
        int x = (i < nb) ? bsum[i] : 0;
        int v = x;
#pragma unroll
        for (int off = 1; off < 64; off <<= 1) {
            int tv = __shfl_up(v, off, 64);
            if (lane >= off) v += tv;
        }
        int excl = run + v - x;
        if (i < nb) bsum[i] = excl;
        __syncthreads();
        if (lane == 63) run = excl + x;
        __syncthreads();
    }
}

__global__ void scan3_kernel(int* __restrict__ row_ptr,
                             const int* __restrict__ bsum, int n, int total)
{
    int i = blockIdx.x * blockDim.x + threadIdx.x;
    if (i < n) row_ptr[i] += bsum[i >> 10];
    if (i == 0) row_ptr[n] = total;
}

// CSR build, pass 2: slot_of[i] = row_ptr[dst[i]] + r[i], in place on r.
__global__ void slots_kernel(const int* __restrict__ dst,
                             const int* __restrict__ row_ptr,
                             int* __restrict__ r, int n)
{
    int i = blockIdx.x * blockDim.x + threadIdx.x;
    if (i < n) r[i] = row_ptr[dst[i]] + r[i];
}

// ---------------------------------------------------------------------------
// Edge kernel: per undirected pair (p, p+E) update both directed messages,
// writing into dst-sorted slots (random 64B-aligned rows, no amplification).
// rev[p] == p+E by construction. Pair exclusively owns its two slots.
// potential = ones + (e-1)*I  =>  (t@pot)[j] = s + (e-1)*t[j], rowsum=(15+e)*s
// ---------------------------------------------------------------------------
template <bool FIRST>
__global__ void edge_kernel(const float* __restrict__ beliefs,
                            float* __restrict__ messages,
                            const int* __restrict__ src,
                            const int* __restrict__ dst,
                            const int* __restrict__ slot_of,
                            int n_pairs)
{
    long long gid = (long long)blockIdx.x * blockDim.x + threadIdx.x;
    int p = (int)(gid >> 2);
    if (p >= n_pairs) return;
    int sub = (int)(gid & 3);

    int u  = src[p];
    int v  = dst[p];
    int sF = slot_of[p];            // slot of edge u->v (dst v)
    int sR = slot_of[p + n_pairs];  // slot of edge v->u (dst u)

    const float EM1  = 1.7182818284590452354f;   // e - 1
    const float SUMF = 17.718281828459045235f;   // 15 + e

    float4 bu = ld4(beliefs + (size_t)u * NSTATES + sub * 4);
    float4 bv = ld4(beliefs + (size_t)v * NSTATES + sub * 4);

    float4 tf, tr;
    if (FIRST) {
        // messages are exactly 1/16 -> t = 16*b (exact)
        tf = make_float4(bu.x * 16.f, bu.y * 16.f, bu.z * 16.f, bu.w * 16.f);
        tr = make_float4(bv.x * 16.f, bv.y * 16.f, bv.z * 16.f, bv.w * 16.f);
    } else {
        float4 mf = ld4(messages + (size_t)sF * NSTATES + sub * 4);
        float4 mr = ld4(messages + (size_t)sR * NSTATES + sub * 4);
        tf = make_float4(bu.x / mr.x, bu.y / mr.y, bu.z / mr.z, bu.w / mr.w);
        tr = make_float4(bv.x / mf.x, bv.y / mf.y, bv.z / mf.z, bv.w / mf.w);
    }

    float sf = (tf.x + tf.y) + (tf.z + tf.w);
    float sr = (tr.x + tr.y) + (tr.z + tr.w);
    sf += __shfl_xor(sf, 1, 64);
    sf += __shfl_xor(sf, 2, 64);
    sr += __shfl_xor(sr, 1, 64);
    sr += __shfl_xor(sr, 2, 64);

    float invf = 1.0f / (SUMF * sf);
    float invr = 1.0f / (SUMF * sr);

    float4 nf, nr;
    nf.x = fmaf(EM1, tf.x, sf) * invf;
    nf.y = fmaf(EM1, tf.y, sf) * invf;
    nf.z = fmaf(EM1, tf.z, sf) * invf;
    nf.w = fmaf(EM1, tf.w, sf) * invf;
    nr.x = fmaf(EM1, tr.x, sr) * invr;
    nr.y = fmaf(EM1, tr.y, sr) * invr;
    nr.z = fmaf(EM1, tr.z, sr) * invr;
    nr.w = fmaf(EM1, tr.w, sr) * invr;

    st4(messages + (size_t)sF * NSTATES + sub * 4, nf);
    st4(messages + (size_t)sR * NSTATES + sub * 4, nr);
}

// ---------------------------------------------------------------------------
// Belief kernel: one wave per node. Messages for the node are CONTIGUOUS in
// [row_ptr[v], row_ptr[v+1]) -> fully sequential reads. Lanes: 4 rows x 16
// states per step. Writes softmax(log_priors + sum log m).
// ---------------------------------------------------------------------------
__global__ void belief_kernel(const float* __restrict__ messages,
                              const int* __restrict__ row_ptr,
                              const float* __restrict__ log_priors,
                              float* __restrict__ beliefs,
                              int n_nodes)
{
    long long gid = (long long)blockIdx.x * blockDim.x + threadIdx.x;
    int node = (int)(gid >> 6);
    if (node >= n_nodes) return;
    int lane = threadIdx.x & 63;
    int s    = lane & 15;
    int rg   = lane >> 4;   // 0..3

    int start = row_ptr[node];
    int end   = row_ptr[node + 1];

    float acc = 0.f;
    for (int row = start + rg; row < end; row += 4) {
        float m = messages[(size_t)row * NSTATES + s];
        acc += logf(fmaxf(m, 1e-10f));
    }
    acc += __shfl_xor(acc, 16, 64);
    acc += __shfl_xor(acc, 32, 64);

    float lb = acc + log_priors[(size_t)node * NSTATES + s];

    float mx = lb;
#pragma unroll
    for (int off = 1; off < 16; off <<= 1)
        mx = fmaxf(mx, __shfl_xor(mx, off, 64));
    float e_ = expf(lb - mx);
    float sm = e_;
#pragma unroll
    for (int off = 1; off < 16; off <<= 1)
        sm += __shfl_xor(sm, off, 64);
    float b = e_ / sm;

    if (rg == 0)
        beliefs[(size_t)node * NSTATES + s] = b;
}

// ---------------------------------------------------------------------------
extern "C" void kernel_launch(void* const* d_in, const int* in_sizes, int n_in,
                              void* d_out, int out_size, void* d_ws, size_t ws_size,
                              hipStream_t stream)
{
    const float* feat = (const float*)d_in[0];
    const float* W    = (const float*)d_in[1];
    const int*   src  = (const int*)d_in[2];
    const int*   dst  = (const int*)d_in[3];

    int n_nodes = in_sizes[0] / 128;
    int n_dir   = in_sizes[2];
    int n_pairs = n_dir / 2;

    float* out         = (float*)d_out;
    float* priors_out  = out;                               // [n_nodes*16]
    float* beliefs     = out + (size_t)n_nodes * NSTATES;   // working + final

    size_t NN16 = (size_t)n_nodes * NSTATES;
    size_t ME   = (size_t)n_dir * NSTATES;

    float* ws         = (float*)d_ws;
    float* log_priors = ws;                         // NN16 f32
    float* messages   = log_priors + NN16;          // ME f32 (dst-sorted)
    int*   slot_of    = (int*)(messages + ME);      // n_dir (rank, then slot)
    int*   row_ptr    = slot_of + n_dir;            // n_nodes+1
    int*   cnt        = row_ptr + n_nodes + 1;      // n_nodes
    int*   bsum       = cnt + n_nodes;              // ~n_nodes/1024

    const int BLK = 256;
    int nb    = (n_nodes + 1023) / 1024;
    int grid1 = (int)((NN16 + BLK - 1) / BLK);                 // 16 lanes/node
    int gridE = (int)(((size_t)n_pairs * 4 + BLK - 1) / BLK);  // 4 lanes/pair
    int gridH = (n_dir + BLK - 1) / BLK;                       // 1 lane/edge
    int gridN = (n_nodes + BLK - 1) / BLK;
    int gridB = (int)(((size_t)n_nodes * 64 + BLK - 1) / BLK); // wave/node

    // --- CSR build: one atomic pass + hierarchical scan + slot resolve ---
    hipMemsetAsync(cnt, 0, (size_t)n_nodes * sizeof(int), stream);
    rank_kernel<<<gridH, BLK, 0, stream>>>(dst, cnt, slot_of, n_dir);
    scan1_kernel<<<nb, 256, 0, stream>>>(cnt, row_ptr, bsum, n_nodes);
    scan2_kernel<<<1, 64, 0, stream>>>(bsum, nb);
    scan3_kernel<<<gridN, BLK, 0, stream>>>(row_ptr, bsum, n_nodes, n_dir);
    slots_kernel<<<gridH, BLK, 0, stream>>>(dst, row_ptr, slot_of, n_dir);

    // --- priors / init ---
    priors_kernel<<<grid1, BLK, 0, stream>>>(feat, W, priors_out, beliefs,
                                             log_priors, n_nodes);

    // --- 3 diffusion iterations ---
    edge_kernel<true><<<gridE, BLK, 0, stream>>>(beliefs, messages, src, dst,
                                                 slot_of, n_pairs);
    belief_kernel<<<gridB, BLK, 0, stream>>>(messages, row_ptr, log_priors,
                                             beliefs, n_nodes);

    edge_kernel<false><<<gridE, BLK, 0, stream>>>(beliefs, messages, src, dst,
                                                  slot_of, n_pairs);
    belief_kernel<<<gridB, BLK, 0, stream>>>(messages, row_ptr, log_priors,
                                             beliefs, n_nodes);

    edge_kernel<false><<<gridE, BLK, 0, stream>>>(beliefs, messages, src, dst,
                                                  slot_of, n_pairs);
    belief_kernel<<<gridB, BLK, 0, stream>>>(messages, row_ptr, log_priors,
                                             beliefs, n_nodes);
}

// Round 8
// 815.660 us; speedup vs baseline: 2.5284x; 1.0668x over previous
//
#include <hip/hip_runtime.h>
#include <hip/hip_fp16.h>

#define NSTATES 16

static __device__ __forceinline__ float4 ld4(const float* p) {
    return *reinterpret_cast<const float4*>(p);
}

// 4 halfs = 8 bytes, loaded/stored as one dwordx2
struct h4 { __half2 a, b; };

static __device__ __forceinline__ float4 ldh4(const __half* p) {
    h4 v = *reinterpret_cast<const h4*>(p);
    float2 fa = __half22float2(v.a);
    float2 fb = __half22float2(v.b);
    return make_float4(fa.x, fa.y, fb.x, fb.y);
}
static __device__ __forceinline__ void sth4(__half* p, float4 f) {
    h4 v;
    v.a = __floats2half2_rn(f.x, f.y);
    v.b = __floats2half2_rn(f.z, f.w);
    *reinterpret_cast<h4*>(p) = v;
}

// ---------------------------------------------------------------------------
// Priors: softmax(features @ W); init working beliefs + log_priors.
// 16 lanes per node, one state per lane. W staged in LDS (8 KB).
// ---------------------------------------------------------------------------
__global__ void priors_kernel(const float* __restrict__ feat,
                              const float* __restrict__ W,
                              float* __restrict__ priors_out,
                              float* __restrict__ beliefs,
                              float* __restrict__ log_priors,
                              int n_nodes)
{
    __shared__ float Wl[128 * NSTATES];
    for (int i = threadIdx.x; i < 128 * NSTATES; i += blockDim.x)
        Wl[i] = W[i];
    __syncthreads();

    long long gid = (long long)blockIdx.x * blockDim.x + threadIdx.x;
    int node = (int)(gid >> 4);
    if (node >= n_nodes) return;
    int s = (int)(gid & 15);

    const float4* f4 = reinterpret_cast<const float4*>(feat + (size_t)node * 128);
    float acc = 0.f;
#pragma unroll
    for (int i = 0; i < 32; ++i) {
        float4 f = f4[i];
        acc = fmaf(f.x, Wl[(i * 4 + 0) * NSTATES + s], acc);
        acc = fmaf(f.y, Wl[(i * 4 + 1) * NSTATES + s], acc);
        acc = fmaf(f.z, Wl[(i * 4 + 2) * NSTATES + s], acc);
        acc = fmaf(f.w, Wl[(i * 4 + 3) * NSTATES + s], acc);
    }
    float mx = acc;
#pragma unroll
    for (int off = 1; off < 16; off <<= 1)
        mx = fmaxf(mx, __shfl_xor(mx, off, 64));
    float ex = expf(acc - mx);
    float sm = ex;
#pragma unroll
    for (int off = 1; off < 16; off <<= 1)
        sm += __shfl_xor(sm, off, 64);
    float p = ex / sm;

    size_t idx = (size_t)node * NSTATES + s;
    priors_out[idx] = p;
    beliefs[idx]    = p;
    log_priors[idx] = logf(fmaxf(p, 1e-10f));
}

// ---------------------------------------------------------------------------
// CSR build, pass 1: per-edge within-dst rank + degree histogram.
// ---------------------------------------------------------------------------
__global__ void rank_kernel(const int* __restrict__ dst, int* __restrict__ cnt,
                            int* __restrict__ r, int n)
{
    int i = blockIdx.x * blockDim.x + threadIdx.x;
    if (i < n) r[i] = atomicAdd(&cnt[dst[i]], 1);
}

// ---------------------------------------------------------------------------
// Hierarchical exclusive scan of cnt[0..n) -> row_ptr. 1024 elements/block.
// ---------------------------------------------------------------------------
__global__ void scan1_kernel(const int* __restrict__ cnt,
                             int* __restrict__ row_ptr,
                             int* __restrict__ bsum, int n)
{
    int base = blockIdx.x * 1024;
    int t = threadIdx.x;            // 0..255
    int i0 = base + t * 4;
    int a0 = (i0 + 0 < n) ? cnt[i0 + 0] : 0;
    int a1 = (i0 + 1 < n) ? cnt[i0 + 1] : 0;
    int a2 = (i0 + 2 < n) ? cnt[i0 + 2] : 0;
    int a3 = (i0 + 3 < n) ? cnt[i0 + 3] : 0;
    int sl = a0 + a1 + a2 + a3;

    int lane = t & 63, wid = t >> 6;
    int v = sl;
#pragma unroll
    for (int off = 1; off < 64; off <<= 1) {
        int tv = __shfl_up(v, off, 64);
        if (lane >= off) v += tv;
    }
    __shared__ int wtot[4], woff[4];
    if (lane == 63) wtot[wid] = v;
    __syncthreads();
    if (t == 0) {
        int a = 0;
        for (int w = 0; w < 4; ++w) { woff[w] = a; a += wtot[w]; }
        bsum[blockIdx.x] = a;
    }
    __syncthreads();
    int excl = woff[wid] + (v - sl);
    if (i0 + 0 < n) row_ptr[i0 + 0] = excl;
    if (i0 + 1 < n) row_ptr[i0 + 1] = excl + a0;
    if (i0 + 2 < n) row_ptr[i0 + 2] = excl + a0 + a1;
    if (i0 + 3 < n) row_ptr[i0 + 3] = excl + a0 + a1 + a2;
}

// single wave scans the ~98 block sums in place (exclusive)
__global__ void scan2_kernel(int* __restrict__ bsum, int nb)
{
    __shared__ int run;
    int lane = threadIdx.x;
    if (lane == 0) run = 0;
    __syncthreads();
    for (int b = 0; b < nb; b += 64) {
        int i = b + lane;
        int x = (i < nb) ? bsum[i] : 0;
        int v = x;
#pragma unroll
        for (int off = 1; off < 64; off <<= 1) {
            int tv = __shfl_up(v, off, 64);
            if (lane >= off) v += tv;
        }
        int excl = run + v - x;
        if (i < nb) bsum[i] = excl;
        __syncthreads();
        if (lane == 63) run = excl + x;
        __syncthreads();
    }
}

__global__ void scan3_kernel(int* __restrict__ row_ptr,
                             const int* __restrict__ bsum, int n, int total)
{
    int i = blockIdx.x * blockDim.x + threadIdx.x;
    if (i < n) row_ptr[i] += bsum[i >> 10];
    if (i == 0) row_ptr[n] = total;
}

// CSR build, pass 2: slot_of[i] = row_ptr[dst[i]] + r[i], in place on r.
__global__ void slots_kernel(const int* __restrict__ dst,
                             const int* __restrict__ row_ptr,
                             int* __restrict__ r, int n)
{
    int i = blockIdx.x * blockDim.x + threadIdx.x;
    if (i < n) r[i] = row_ptr[dst[i]] + r[i];
}

// ---------------------------------------------------------------------------
// Edge kernel: per undirected pair (p, p+E) update both directed messages,
// fp16 storage in dst-sorted slots. Pair exclusively owns its two slots.
// Messages live in [1/(15+e), e/(15+e)] ~ [0.056,0.153] -> fp16-safe.
// potential = ones + (e-1)*I  =>  (t@pot)[j] = s + (e-1)*t[j], rowsum=(15+e)*s
// ---------------------------------------------------------------------------
template <bool FIRST>
__global__ void edge_kernel(const float* __restrict__ beliefs,
                            __half* __restrict__ messages,
                            const int* __restrict__ src,
                            const int* __restrict__ dst,
                            const int* __restrict__ slot_of,
                            int n_pairs)
{
    long long gid = (long long)blockIdx.x * blockDim.x + threadIdx.x;
    int p = (int)(gid >> 2);
    if (p >= n_pairs) return;
    int sub = (int)(gid & 3);

    int u  = src[p];
    int v  = dst[p];
    int sF = slot_of[p];            // slot of edge u->v (in v's row block)
    int sR = slot_of[p + n_pairs];  // slot of edge v->u (in u's row block)

    const float EM1  = 1.7182818284590452354f;   // e - 1
    const float SUMF = 17.718281828459045235f;   // 15 + e

    float4 bu = ld4(beliefs + (size_t)u * NSTATES + sub * 4);
    float4 bv = ld4(beliefs + (size_t)v * NSTATES + sub * 4);

    float4 tf, tr;
    if (FIRST) {
        // messages are exactly 1/16 -> t = 16*b (exact)
        tf = make_float4(bu.x * 16.f, bu.y * 16.f, bu.z * 16.f, bu.w * 16.f);
        tr = make_float4(bv.x * 16.f, bv.y * 16.f, bv.z * 16.f, bv.w * 16.f);
    } else {
        float4 mf = ldh4(messages + (size_t)sF * NSTATES + sub * 4);
        float4 mr = ldh4(messages + (size_t)sR * NSTATES + sub * 4);
        tf = make_float4(bu.x / mr.x, bu.y / mr.y, bu.z / mr.z, bu.w / mr.w);
        tr = make_float4(bv.x / mf.x, bv.y / mf.y, bv.z / mf.z, bv.w / mf.w);
    }

    float sf = (tf.x + tf.y) + (tf.z + tf.w);
    float sr = (tr.x + tr.y) + (tr.z + tr.w);
    sf += __shfl_xor(sf, 1, 64);
    sf += __shfl_xor(sf, 2, 64);
    sr += __shfl_xor(sr, 1, 64);
    sr += __shfl_xor(sr, 2, 64);

    float invf = 1.0f / (SUMF * sf);
    float invr = 1.0f / (SUMF * sr);

    float4 nf, nr;
    nf.x = fmaf(EM1, tf.x, sf) * invf;
    nf.y = fmaf(EM1, tf.y, sf) * invf;
    nf.z = fmaf(EM1, tf.z, sf) * invf;
    nf.w = fmaf(EM1, tf.w, sf) * invf;
    nr.x = fmaf(EM1, tr.x, sr) * invr;
    nr.y = fmaf(EM1, tr.y, sr) * invr;
    nr.z = fmaf(EM1, tr.z, sr) * invr;
    nr.w = fmaf(EM1, tr.w, sr) * invr;

    sth4(messages + (size_t)sF * NSTATES + sub * 4, nf);
    sth4(messages + (size_t)sR * NSTATES + sub * 4, nr);
}

// ---------------------------------------------------------------------------
// Belief kernel: one wave per node. Node's incoming messages are CONTIGUOUS
// in [row_ptr[v], row_ptr[v+1]) -> sequential fp16 reads, 8 rows/step.
// Lane = rg(0..7) x cp(0..7); lane covers states {2cp, 2cp+1}.
// ---------------------------------------------------------------------------
__global__ void belief_kernel(const __half* __restrict__ messages,
                              const int* __restrict__ row_ptr,
                              const float* __restrict__ log_priors,
                              float* __restrict__ beliefs,
                              int n_nodes)
{
    long long gid = (long long)blockIdx.x * blockDim.x + threadIdx.x;
    int node = (int)(gid >> 6);
    if (node >= n_nodes) return;
    int lane = threadIdx.x & 63;
    int cp   = lane & 7;    // column pair: states 2cp, 2cp+1
    int rg   = lane >> 3;   // 0..7 row group

    int start = row_ptr[node];
    int end   = row_ptr[node + 1];

    float acc0 = 0.f, acc1 = 0.f;
    for (int row = start + rg; row < end; row += 8) {
        __half2 m2 = *reinterpret_cast<const __half2*>(
            messages + (size_t)row * NSTATES + cp * 2);
        float2 f = __half22float2(m2);
        acc0 += logf(fmaxf(f.x, 1e-10f));
        acc1 += logf(fmaxf(f.y, 1e-10f));
    }
    // reduce across the 8 row groups (lanes sharing cp)
#pragma unroll
    for (int off = 8; off < 64; off <<= 1) {
        acc0 += __shfl_xor(acc0, off, 64);
        acc1 += __shfl_xor(acc1, off, 64);
    }

    float2 lp = *reinterpret_cast<const float2*>(
        log_priors + (size_t)node * NSTATES + cp * 2);
    float lb0 = acc0 + lp.x;
    float lb1 = acc1 + lp.y;

    float mx = fmaxf(lb0, lb1);
#pragma unroll
    for (int off = 1; off < 8; off <<= 1)
        mx = fmaxf(mx, __shfl_xor(mx, off, 64));
    float e0 = expf(lb0 - mx);
    float e1 = expf(lb1 - mx);
    float sm = e0 + e1;
#pragma unroll
    for (int off = 1; off < 8; off <<= 1)
        sm += __shfl_xor(sm, off, 64);
    float inv = 1.0f / sm;

    if (rg == 0) {
        float2 b = make_float2(e0 * inv, e1 * inv);
        *reinterpret_cast<float2*>(beliefs + (size_t)node * NSTATES + cp * 2) = b;
    }
}

// ---------------------------------------------------------------------------
extern "C" void kernel_launch(void* const* d_in, const int* in_sizes, int n_in,
                              void* d_out, int out_size, void* d_ws, size_t ws_size,
                              hipStream_t stream)
{
    const float* feat = (const float*)d_in[0];
    const float* W    = (const float*)d_in[1];
    const int*   src  = (const int*)d_in[2];
    const int*   dst  = (const int*)d_in[3];

    int n_nodes = in_sizes[0] / 128;
    int n_dir   = in_sizes[2];
    int n_pairs = n_dir / 2;

    float* out         = (float*)d_out;
    float* priors_out  = out;                               // [n_nodes*16]
    float* beliefs     = out + (size_t)n_nodes * NSTATES;   // working + final

    size_t NN16 = (size_t)n_nodes * NSTATES;
    size_t ME   = (size_t)n_dir * NSTATES;

    float*  ws         = (float*)d_ws;
    float*  log_priors = ws;                          // NN16 f32
    __half* messages   = (__half*)(log_priors + NN16);// ME fp16 (dst-sorted)
    int*    slot_of    = (int*)(messages + ME);       // n_dir (rank->slot)
    int*    row_ptr    = slot_of + n_dir;             // n_nodes+1
    int*    cnt        = row_ptr + n_nodes + 1;       // n_nodes
    int*    bsum       = cnt + n_nodes;               // ~n_nodes/1024

    const int BLK = 256;
    int nb    = (n_nodes + 1023) / 1024;
    int grid1 = (int)((NN16 + BLK - 1) / BLK);                 // 16 lanes/node
    int gridE = (int)(((size_t)n_pairs * 4 + BLK - 1) / BLK);  // 4 lanes/pair
    int gridH = (n_dir + BLK - 1) / BLK;                       // 1 lane/edge
    int gridN = (n_nodes + BLK - 1) / BLK;
    int gridB = (int)(((size_t)n_nodes * 64 + BLK - 1) / BLK); // wave/node

    // --- CSR build: one atomic pass + hierarchical scan + slot resolve ---
    hipMemsetAsync(cnt, 0, (size_t)n_nodes * sizeof(int), stream);
    rank_kernel<<<gridH, BLK, 0, stream>>>(dst, cnt, slot_of, n_dir);
    scan1_kernel<<<nb, 256, 0, stream>>>(cnt, row_ptr, bsum, n_nodes);
    scan2_kernel<<<1, 64, 0, stream>>>(bsum, nb);
    scan3_kernel<<<gridN, BLK, 0, stream>>>(row_ptr, bsum, n_nodes, n_dir);
    slots_kernel<<<gridH, BLK, 0, stream>>>(dst, row_ptr, slot_of, n_dir);

    // --- priors / init ---
    priors_kernel<<<grid1, BLK, 0, stream>>>(feat, W, priors_out, beliefs,
                                             log_priors, n_nodes);

    // --- 3 diffusion iterations ---
    edge_kernel<true><<<gridE, BLK, 0, stream>>>(beliefs, messages, src, dst,
                                                 slot_of, n_pairs);
    belief_kernel<<<gridB, BLK, 0, stream>>>(messages, row_ptr, log_priors,
                                             beliefs, n_nodes);

    edge_kernel<false><<<gridE, BLK, 0, stream>>>(beliefs, messages, src, dst,
                                                  slot_of, n_pairs);
    belief_kernel<<<gridB, BLK, 0, stream>>>(messages, row_ptr, log_priors,
                                             beliefs, n_nodes);

    edge_kernel<false><<<gridE, BLK, 0, stream>>>(beliefs, messages, src, dst,
                                                  slot_of, n_pairs);
    belief_kernel<<<gridB, BLK, 0, stream>>>(messages, row_ptr, log_priors,
                                             beliefs, n_nodes);
}

// Round 9
// 760.472 us; speedup vs baseline: 2.7119x; 1.0726x over previous
//
#include <hip/hip_runtime.h>
#include <hip/hip_fp16.h>

#define NSTATES 16
#define P_PART 4
#define C_CHUNK 32

static __device__ __forceinline__ float4 ld4(const float* p) {
    return *reinterpret_cast<const float4*>(p);
}

// 4 halfs = 8 bytes, loaded/stored as one dwordx2
struct h4 { __half2 a, b; };

static __device__ __forceinline__ float4 ldh4(const __half* p) {
    h4 v = *reinterpret_cast<const h4*>(p);
    float2 fa = __half22float2(v.a);
    float2 fb = __half22float2(v.b);
    return make_float4(fa.x, fa.y, fb.x, fb.y);
}
static __device__ __forceinline__ void sth4(__half* p, float4 f) {
    h4 v;
    v.a = __floats2half2_rn(f.x, f.y);
    v.b = __floats2half2_rn(f.z, f.w);
    *reinterpret_cast<h4*>(p) = v;
}

// ---------------------------------------------------------------------------
// Priors: softmax(features @ W); init working beliefs + log_priors.
// ---------------------------------------------------------------------------
__global__ void priors_kernel(const float* __restrict__ feat,
                              const float* __restrict__ W,
                              float* __restrict__ priors_out,
                              float* __restrict__ beliefs,
                              float* __restrict__ log_priors,
                              int n_nodes)
{
    __shared__ float Wl[128 * NSTATES];
    for (int i = threadIdx.x; i < 128 * NSTATES; i += blockDim.x)
        Wl[i] = W[i];
    __syncthreads();

    long long gid = (long long)blockIdx.x * blockDim.x + threadIdx.x;
    int node = (int)(gid >> 4);
    if (node >= n_nodes) return;
    int s = (int)(gid & 15);

    const float4* f4 = reinterpret_cast<const float4*>(feat + (size_t)node * 128);
    float acc = 0.f;
#pragma unroll
    for (int i = 0; i < 32; ++i) {
        float4 f = f4[i];
        acc = fmaf(f.x, Wl[(i * 4 + 0) * NSTATES + s], acc);
        acc = fmaf(f.y, Wl[(i * 4 + 1) * NSTATES + s], acc);
        acc = fmaf(f.z, Wl[(i * 4 + 2) * NSTATES + s], acc);
        acc = fmaf(f.w, Wl[(i * 4 + 3) * NSTATES + s], acc);
    }
    float mx = acc;
#pragma unroll
    for (int off = 1; off < 16; off <<= 1)
        mx = fmaxf(mx, __shfl_xor(mx, off, 64));
    float ex = expf(acc - mx);
    float sm = ex;
#pragma unroll
    for (int off = 1; off < 16; off <<= 1)
        sm += __shfl_xor(sm, off, 64);
    float p = ex / sm;

    size_t idx = (size_t)node * NSTATES + s;
    priors_out[idx] = p;
    beliefs[idx]    = p;
    log_priors[idx] = logf(fmaxf(p, 1e-10f));
}

// ---------------------------------------------------------------------------
// Atomic-free CSR build (radix-style, LDS histograms only).
// Pass 1: block (p,c) counts chunk c's dst values in node-range p into LDS,
// writes percount[c][node] (streaming). No global atomics.
// ---------------------------------------------------------------------------
__global__ void __launch_bounds__(1024) hist1_kernel(
    const int* __restrict__ dst, int* __restrict__ percount,
    int n, int n_nodes, int bins, int chunk)
{
    extern __shared__ int lh[];
    int c = blockIdx.x & (C_CHUNK - 1);
    int p = blockIdx.x / C_CHUNK;
    int base = p * bins;
    for (int i = threadIdx.x; i < bins; i += 1024) lh[i] = 0;
    __syncthreads();
    int lo = c * chunk, hi = min(lo + chunk, n);
    for (int i = lo + threadIdx.x; i < hi; i += 1024) {
        int d = dst[i] - base;
        if ((unsigned)d < (unsigned)bins) atomicAdd(&lh[d], 1);
    }
    __syncthreads();
    int lim = min(bins, n_nodes - base);
    int* out = percount + (size_t)c * n_nodes + base;
    for (int i = threadIdx.x; i < lim; i += 1024) out[i] = lh[i];
}

// Pass 2: per node, exclusive scan over the C chunk-counts (in place) and
// total degree -> cnt. Fully writes cnt (no memset needed).
__global__ void colscan_kernel(int* __restrict__ percount,
                               int* __restrict__ cnt, int n_nodes)
{
    int v = blockIdx.x * blockDim.x + threadIdx.x;
    if (v >= n_nodes) return;
    int acc = 0;
#pragma unroll
    for (int c = 0; c < C_CHUNK; ++c) {
        size_t idx = (size_t)c * n_nodes + v;
        int x = percount[idx];
        percount[idx] = acc;    // exclusive chunk offset
        acc += x;
    }
    cnt[v] = acc;
}

// ---------------------------------------------------------------------------
// Hierarchical exclusive scan of cnt[0..n) -> row_ptr. 1024 elements/block.
// ---------------------------------------------------------------------------
__global__ void scan1_kernel(const int* __restrict__ cnt,
                             int* __restrict__ row_ptr,
                             int* __restrict__ bsum, int n)
{
    int base = blockIdx.x * 1024;
    int t = threadIdx.x;            // 0..255
    int i0 = base + t * 4;
    int a0 = (i0 + 0 < n) ? cnt[i0 + 0] : 0;
    int a1 = (i0 + 1 < n) ? cnt[i0 + 1] : 0;
    int a2 = (i0 + 2 < n) ? cnt[i0 + 2] : 0;
    int a3 = (i0 + 3 < n) ? cnt[i0 + 3] : 0;
    int sl = a0 + a1 + a2 + a3;

    int lane = t & 63, wid = t >> 6;
    int v = sl;
#pragma unroll
    for (int off = 1; off < 64; off <<= 1) {
        int tv = __shfl_up(v, off, 64);
        if (lane >= off) v += tv;
    }
    __shared__ int wtot[4], woff[4];
    if (lane == 63) wtot[wid] = v;
    __syncthreads();
    if (t == 0) {
        int a = 0;
        for (int w = 0; w < 4; ++w) { woff[w] = a; a += wtot[w]; }
        bsum[blockIdx.x] = a;
    }
    __syncthreads();
    int excl = woff[wid] + (v - sl);
    if (i0 + 0 < n) row_ptr[i0 + 0] = excl;
    if (i0 + 1 < n) row_ptr[i0 + 1] = excl + a0;
    if (i0 + 2 < n) row_ptr[i0 + 2] = excl + a0 + a1;
    if (i0 + 3 < n) row_ptr[i0 + 3] = excl + a0 + a1 + a2;
}

// single wave scans the block sums in place (exclusive)
__global__ void scan2_kernel(int* __restrict__ bsum, int nb)
{
    __shared__ int run;
    int lane = threadIdx.x;
    if (lane == 0) run = 0;
    __syncthreads();
    for (int b = 0; b < nb; b += 64) {
        int i = b + lane;
        int x = (i < nb) ? bsum[i] : 0;
        int v = x;
#pragma unroll
        for (int off = 1; off < 64; off <<= 1) {
            int tv = __shfl_up(v, off, 64);
            if (lane >= off) v += tv;
        }
        int excl = run + v - x;
        if (i < nb) bsum[i] = excl;
        __syncthreads();
        if (lane == 63) run = excl + x;
        __syncthreads();
    }
}

__global__ void scan3_kernel(int* __restrict__ row_ptr,
                             const int* __restrict__ bsum, int n, int total)
{
    int i = blockIdx.x * blockDim.x + threadIdx.x;
    if (i < n) row_ptr[i] += bsum[i >> 10];
    if (i == 0) row_ptr[n] = total;
}

// Pass 3: recompute within-chunk ranks via LDS atomics (reproduces pass-1
// counts exactly); slot_of[i] = row_ptr[d] + chunkoff[c][d] + lrank.
// slot_of writes are sequential (i in chunk order). No global atomics.
__global__ void __launch_bounds__(1024) slot3_kernel(
    const int* __restrict__ dst, const int* __restrict__ row_ptr,
    const int* __restrict__ percount, int* __restrict__ slot_of,
    int n, int n_nodes, int bins, int chunk)
{
    extern __shared__ int lh[];
    int c = blockIdx.x & (C_CHUNK - 1);
    int p = blockIdx.x / C_CHUNK;
    int base = p * bins;
    for (int i = threadIdx.x; i < bins; i += 1024) lh[i] = 0;
    __syncthreads();
    int lo = c * chunk, hi = min(lo + chunk, n);
    const int* pc = percount + (size_t)c * n_nodes;
    for (int i = lo + threadIdx.x; i < hi; i += 1024) {
        int d = dst[i];
        int ld = d - base;
        if ((unsigned)ld < (unsigned)bins) {
            int lr = atomicAdd(&lh[ld], 1);
            slot_of[i] = row_ptr[d] + pc[d] + lr;
        }
    }
}

// ---------------------------------------------------------------------------
// Edge kernel: per undirected pair (p, p+E) update both directed messages,
// fp16 storage in dst-sorted slots. Pair exclusively owns its two slots.
// Messages live in [1/(15+e), e/(15+e)] ~ [0.056,0.153] -> fp16-safe.
// potential = ones + (e-1)*I  =>  (t@pot)[j] = s + (e-1)*t[j], rowsum=(15+e)*s
// ---------------------------------------------------------------------------
template <bool FIRST>
__global__ void edge_kernel(const float* __restrict__ beliefs,
                            __half* __restrict__ messages,
                            const int* __restrict__ src,
                            const int* __restrict__ dst,
                            const int* __restrict__ slot_of,
                            int n_pairs)
{
    long long gid = (long long)blockIdx.x * blockDim.x + threadIdx.x;
    int p = (int)(gid >> 2);
    if (p >= n_pairs) return;
    int sub = (int)(gid & 3);

    int u  = src[p];
    int v  = dst[p];
    int sF = slot_of[p];            // slot of edge u->v (in v's row block)
    int sR = slot_of[p + n_pairs];  // slot of edge v->u (in u's row block)

    const float EM1  = 1.7182818284590452354f;   // e - 1
    const float SUMF = 17.718281828459045235f;   // 15 + e

    float4 bu = ld4(beliefs + (size_t)u * NSTATES + sub * 4);
    float4 bv = ld4(beliefs + (size_t)v * NSTATES + sub * 4);

    float4 tf, tr;
    if (FIRST) {
        // messages are exactly 1/16 -> t = 16*b (exact)
        tf = make_float4(bu.x * 16.f, bu.y * 16.f, bu.z * 16.f, bu.w * 16.f);
        tr = make_float4(bv.x * 16.f, bv.y * 16.f, bv.z * 16.f, bv.w * 16.f);
    } else {
        float4 mf = ldh4(messages + (size_t)sF * NSTATES + sub * 4);
        float4 mr = ldh4(messages + (size_t)sR * NSTATES + sub * 4);
        tf = make_float4(bu.x / mr.x, bu.y / mr.y, bu.z / mr.z, bu.w / mr.w);
        tr = make_float4(bv.x / mf.x, bv.y / mf.y, bv.z / mf.z, bv.w / mf.w);
    }

    float sf = (tf.x + tf.y) + (tf.z + tf.w);
    float sr = (tr.x + tr.y) + (tr.z + tr.w);
    sf += __shfl_xor(sf, 1, 64);
    sf += __shfl_xor(sf, 2, 64);
    sr += __shfl_xor(sr, 1, 64);
    sr += __shfl_xor(sr, 2, 64);

    float invf = 1.0f / (SUMF * sf);
    float invr = 1.0f / (SUMF * sr);

    float4 nf, nr;
    nf.x = fmaf(EM1, tf.x, sf) * invf;
    nf.y = fmaf(EM1, tf.y, sf) * invf;
    nf.z = fmaf(EM1, tf.z, sf) * invf;
    nf.w = fmaf(EM1, tf.w, sf) * invf;
    nr.x = fmaf(EM1, tr.x, sr) * invr;
    nr.y = fmaf(EM1, tr.y, sr) * invr;
    nr.z = fmaf(EM1, tr.z, sr) * invr;
    nr.w = fmaf(EM1, tr.w, sr) * invr;

    sth4(messages + (size_t)sF * NSTATES + sub * 4, nf);
    sth4(messages + (size_t)sR * NSTATES + sub * 4, nr);
}

// ---------------------------------------------------------------------------
// Belief kernel: one wave per node. Node's incoming messages are CONTIGUOUS
// in [row_ptr[v], row_ptr[v+1]) -> sequential fp16 reads, 8 rows/step.
// ---------------------------------------------------------------------------
__global__ void belief_kernel(const __half* __restrict__ messages,
                              const int* __restrict__ row_ptr,
                              const float* __restrict__ log_priors,
                              float* __restrict__ beliefs,
                              int n_nodes)
{
    long long gid = (long long)blockIdx.x * blockDim.x + threadIdx.x;
    int node = (int)(gid >> 6);
    if (node >= n_nodes) return;
    int lane = threadIdx.x & 63;
    int cp   = lane & 7;    // column pair: states 2cp, 2cp+1
    int rg   = lane >> 3;   // 0..7 row group

    int start = row_ptr[node];
    int end   = row_ptr[node + 1];

    float acc0 = 0.f, acc1 = 0.f;
    for (int row = start + rg; row < end; row += 8) {
        __half2 m2 = *reinterpret_cast<const __half2*>(
            messages + (size_t)row * NSTATES + cp * 2);
        float2 f = __half22float2(m2);
        acc0 += logf(fmaxf(f.x, 1e-10f));
        acc1 += logf(fmaxf(f.y, 1e-10f));
    }
#pragma unroll
    for (int off = 8; off < 64; off <<= 1) {
        acc0 += __shfl_xor(acc0, off, 64);
        acc1 += __shfl_xor(acc1, off, 64);
    }

    float2 lp = *reinterpret_cast<const float2*>(
        log_priors + (size_t)node * NSTATES + cp * 2);
    float lb0 = acc0 + lp.x;
    float lb1 = acc1 + lp.y;

    float mx = fmaxf(lb0, lb1);
#pragma unroll
    for (int off = 1; off < 8; off <<= 1)
        mx = fmaxf(mx, __shfl_xor(mx, off, 64));
    float e0 = expf(lb0 - mx);
    float e1 = expf(lb1 - mx);
    float sm = e0 + e1;
#pragma unroll
    for (int off = 1; off < 8; off <<= 1)
        sm += __shfl_xor(sm, off, 64);
    float inv = 1.0f / sm;

    if (rg == 0) {
        float2 b = make_float2(e0 * inv, e1 * inv);
        *reinterpret_cast<float2*>(beliefs + (size_t)node * NSTATES + cp * 2) = b;
    }
}

// ---------------------------------------------------------------------------
extern "C" void kernel_launch(void* const* d_in, const int* in_sizes, int n_in,
                              void* d_out, int out_size, void* d_ws, size_t ws_size,
                              hipStream_t stream)
{
    const float* feat = (const float*)d_in[0];
    const float* W    = (const float*)d_in[1];
    const int*   src  = (const int*)d_in[2];
    const int*   dst  = (const int*)d_in[3];

    int n_nodes = in_sizes[0] / 128;
    int n_dir   = in_sizes[2];
    int n_pairs = n_dir / 2;

    float* out         = (float*)d_out;
    float* priors_out  = out;                               // [n_nodes*16]
    float* beliefs     = out + (size_t)n_nodes * NSTATES;   // working + final

    size_t NN16 = (size_t)n_nodes * NSTATES;
    size_t ME   = (size_t)n_dir * NSTATES;

    float*  ws         = (float*)d_ws;
    float*  log_priors = ws;                          // NN16 f32
    __half* messages   = (__half*)(log_priors + NN16);// ME fp16 (dst-sorted)
    int*    slot_of    = (int*)(messages + ME);       // n_dir
    int*    row_ptr    = slot_of + n_dir;             // n_nodes+1
    int*    cnt        = row_ptr + n_nodes + 1;       // n_nodes
    int*    bsum       = cnt + n_nodes;               // ~n_nodes/1024
    int*    percount   = bsum + ((n_nodes + 1023) / 1024) + 1; // C*n_nodes

    const int BLK = 256;
    int nb    = (n_nodes + 1023) / 1024;
    int bins  = (n_nodes + P_PART - 1) / P_PART;
    int chunk = (n_dir + C_CHUNK - 1) / C_CHUNK;
    int grid1 = (int)((NN16 + BLK - 1) / BLK);                 // 16 lanes/node
    int gridE = (int)(((size_t)n_pairs * 4 + BLK - 1) / BLK);  // 4 lanes/pair
    int gridN = (n_nodes + BLK - 1) / BLK;
    int gridB = (int)(((size_t)n_nodes * 64 + BLK - 1) / BLK); // wave/node

    // --- CSR build: atomic-free (LDS histograms + scans) ---
    hist1_kernel<<<P_PART * C_CHUNK, 1024, bins * sizeof(int), stream>>>(
        dst, percount, n_dir, n_nodes, bins, chunk);
    colscan_kernel<<<gridN, BLK, 0, stream>>>(percount, cnt, n_nodes);
    scan1_kernel<<<nb, 256, 0, stream>>>(cnt, row_ptr, bsum, n_nodes);
    scan2_kernel<<<1, 64, 0, stream>>>(bsum, nb);
    scan3_kernel<<<gridN, BLK, 0, stream>>>(row_ptr, bsum, n_nodes, n_dir);
    slot3_kernel<<<P_PART * C_CHUNK, 1024, bins * sizeof(int), stream>>>(
        dst, row_ptr, percount, slot_of, n_dir, n_nodes, bins, chunk);

    // --- priors / init ---
    priors_kernel<<<grid1, BLK, 0, stream>>>(feat, W, priors_out, beliefs,
                                             log_priors, n_nodes);

    // --- 3 diffusion iterations ---
    edge_kernel<true><<<gridE, BLK, 0, stream>>>(beliefs, messages, src, dst,
                                                 slot_of, n_pairs);
    belief_kernel<<<gridB, BLK, 0, stream>>>(messages, row_ptr, log_priors,
                                             beliefs, n_nodes);

    edge_kernel<false><<<gridE, BLK, 0, stream>>>(beliefs, messages, src, dst,
                                                  slot_of, n_pairs);
    belief_kernel<<<gridB, BLK, 0, stream>>>(messages, row_ptr, log_priors,
                                             beliefs, n_nodes);

    edge_kernel<false><<<gridE, BLK, 0, stream>>>(beliefs, messages, src, dst,
                                                  slot_of, n_pairs);
    belief_kernel<<<gridB, BLK, 0, stream>>>(messages, row_ptr, log_priors,
                                             beliefs, n_nodes);
}

// Round 11
// 691.382 us; speedup vs baseline: 2.9828x; 1.0999x over previous
//
#include <hip/hip_runtime.h>
#include <hip/hip_fp16.h>

#define NSTATES 16
#define P_PART 4
#define C_CHUNK 32

// ---------------------------------------------------------------------------
// Priors + iter-0 message scatter.
// 16 lanes per node: compute p = softmax(feat@W), write priors/log_priors,
// and scatter m_1 = (1+(e-1)p)/(15+e) to every outgoing slot (iter-0 messages
// are uniform 1/16, so sum(t)=16 exactly and m_1 depends only on u).
// ---------------------------------------------------------------------------
__global__ void priors_kernel(const float* __restrict__ feat,
                              const float* __restrict__ W,
                              float* __restrict__ priors_out,
                              float* __restrict__ log_priors,
                              const int* __restrict__ srev,
                              const int* __restrict__ row_ptr,
                              __half* __restrict__ msgs_out,
                              int n_nodes)
{
    __shared__ float Wl[128 * NSTATES];
    for (int i = threadIdx.x; i < 128 * NSTATES; i += blockDim.x)
        Wl[i] = W[i];
    __syncthreads();

    long long gid = (long long)blockIdx.x * blockDim.x + threadIdx.x;
    int node = (int)(gid >> 4);
    if (node >= n_nodes) return;
    int s = (int)(gid & 15);

    const float4* f4 = reinterpret_cast<const float4*>(feat + (size_t)node * 128);
    float acc = 0.f;
#pragma unroll
    for (int i = 0; i < 32; ++i) {
        float4 f = f4[i];
        acc = fmaf(f.x, Wl[(i * 4 + 0) * NSTATES + s], acc);
        acc = fmaf(f.y, Wl[(i * 4 + 1) * NSTATES + s], acc);
        acc = fmaf(f.z, Wl[(i * 4 + 2) * NSTATES + s], acc);
        acc = fmaf(f.w, Wl[(i * 4 + 3) * NSTATES + s], acc);
    }
    float mx = acc;
#pragma unroll
    for (int off = 1; off < 16; off <<= 1)
        mx = fmaxf(mx, __shfl_xor(mx, off, 64));
    float ex = expf(acc - mx);
    float sm = ex;
#pragma unroll
    for (int off = 1; off < 16; off <<= 1)
        sm += __shfl_xor(sm, off, 64);
    float p = ex / sm;

    size_t idx = (size_t)node * NSTATES + s;
    priors_out[idx] = p;
    log_priors[idx] = logf(fmaxf(p, 1e-10f));

    const float EM1  = 1.7182818284590452354f;   // e - 1
    const float SUMF = 17.718281828459045235f;   // 15 + e
    __half h = __float2half((1.f + EM1 * p) * (1.f / SUMF));

    int start = row_ptr[node];
    int end   = row_ptr[node + 1];
    for (int r = start; r < end; ++r) {
        int tgt = srev[r];                         // broadcast within 16 lanes
        msgs_out[(size_t)tgt * NSTATES + s] = h;   // 32B row per step
    }
}

// ---------------------------------------------------------------------------
// Atomic-free CSR build (radix-style, LDS histograms only).
// ---------------------------------------------------------------------------
__global__ void __launch_bounds__(1024) hist1_kernel(
    const int* __restrict__ dst, int* __restrict__ percount,
    int n, int n_nodes, int bins, int chunk)
{
    extern __shared__ int lh[];
    int c = blockIdx.x & (C_CHUNK - 1);
    int p = blockIdx.x / C_CHUNK;
    int base = p * bins;
    for (int i = threadIdx.x; i < bins; i += 1024) lh[i] = 0;
    __syncthreads();
    int lo = c * chunk, hi = min(lo + chunk, n);
    for (int i = lo + threadIdx.x; i < hi; i += 1024) {
        int d = dst[i] - base;
        if ((unsigned)d < (unsigned)bins) atomicAdd(&lh[d], 1);
    }
    __syncthreads();
    int lim = min(bins, n_nodes - base);
    int* out = percount + (size_t)c * n_nodes + base;
    for (int i = threadIdx.x; i < lim; i += 1024) out[i] = lh[i];
}

// per node: exclusive scan over the C chunk-counts (in place) + total -> cnt.
__global__ void colscan_kernel(int* __restrict__ percount,
                               int* __restrict__ cnt, int n_nodes)
{
    int v = blockIdx.x * blockDim.x + threadIdx.x;
    if (v >= n_nodes) return;
    int acc = 0;
#pragma unroll
    for (int c = 0; c < C_CHUNK; ++c) {
        size_t idx = (size_t)c * n_nodes + v;
        int x = percount[idx];
        percount[idx] = acc;
        acc += x;
    }
    cnt[v] = acc;
}

__global__ void scan1_kernel(const int* __restrict__ cnt,
                             int* __restrict__ row_ptr,
                             int* __restrict__ bsum, int n)
{
    int base = blockIdx.x * 1024;
    int t = threadIdx.x;            // 0..255
    int i0 = base + t * 4;
    int a0 = (i0 + 0 < n) ? cnt[i0 + 0] : 0;
    int a1 = (i0 + 1 < n) ? cnt[i0 + 1] : 0;
    int a2 = (i0 + 2 < n) ? cnt[i0 + 2] : 0;
    int a3 = (i0 + 3 < n) ? cnt[i0 + 3] : 0;
    int sl = a0 + a1 + a2 + a3;

    int lane = t & 63, wid = t >> 6;
    int v = sl;
#pragma unroll
    for (int off = 1; off < 64; off <<= 1) {
        int tv = __shfl_up(v, off, 64);
        if (lane >= off) v += tv;
    }
    __shared__ int wtot[4], woff[4];
    if (lane == 63) wtot[wid] = v;
    __syncthreads();
    if (t == 0) {
        int a = 0;
        for (int w = 0; w < 4; ++w) { woff[w] = a; a += wtot[w]; }
        bsum[blockIdx.x] = a;
    }
    __syncthreads();
    int excl = woff[wid] + (v - sl);
    if (i0 + 0 < n) row_ptr[i0 + 0] = excl;
    if (i0 + 1 < n) row_ptr[i0 + 1] = excl + a0;
    if (i0 + 2 < n) row_ptr[i0 + 2] = excl + a0 + a1;
    if (i0 + 3 < n) row_ptr[i0 + 3] = excl + a0 + a1 + a2;
}

__global__ void scan2_kernel(int* __restrict__ bsum, int nb)
{
    __shared__ int run;
    int lane = threadIdx.x;
    if (lane == 0) run = 0;
    __syncthreads();
    for (int b = 0; b < nb; b += 64) {
        int i = b + lane;
        int x = (i < nb) ? bsum[i] : 0;
        int v = x;
#pragma unroll
        for (int off = 1; off < 64; off <<= 1) {
            int tv = __shfl_up(v, off, 64);
            if (lane >= off) v += tv;
        }
        int excl = run + v - x;
        if (i < nb) bsum[i] = excl;
        __syncthreads();
        if (lane == 63) run = excl + x;
        __syncthreads();
    }
}

__global__ void scan3_kernel(int* __restrict__ row_ptr,
                             const int* __restrict__ bsum, int n, int total)
{
    int i = blockIdx.x * blockDim.x + threadIdx.x;
    if (i < n) row_ptr[i] += bsum[i >> 10];
    if (i == 0) row_ptr[n] = total;
}

// slot_of[i] = row_ptr[d] + chunkoff[c][d] + within-chunk rank (LDS atomics).
__global__ void __launch_bounds__(1024) slot3_kernel(
    const int* __restrict__ dst, const int* __restrict__ row_ptr,
    const int* __restrict__ percount, int* __restrict__ slot_of,
    int n, int n_nodes, int bins, int chunk)
{
    extern __shared__ int lh[];
    int c = blockIdx.x & (C_CHUNK - 1);
    int p = blockIdx.x / C_CHUNK;
    int base = p * bins;
    for (int i = threadIdx.x; i < bins; i += 1024) lh[i] = 0;
    __syncthreads();
    int lo = c * chunk, hi = min(lo + chunk, n);
    const int* pc = percount + (size_t)c * n_nodes;
    for (int i = lo + threadIdx.x; i < hi; i += 1024) {
        int d = dst[i];
        int ld = d - base;
        if ((unsigned)ld < (unsigned)bins) {
            int lr = atomicAdd(&lh[ld], 1);
            slot_of[i] = row_ptr[d] + pc[d] + lr;
        }
    }
}

// srev[slot_of[i]] = slot_of[rev_i]. Radix-partitioned by target slot range so
// the 4B scatters land in an L2-resident ~3.2MB window (no write blowup).
__global__ void __launch_bounds__(1024) srev_kernel(
    const int* __restrict__ slot_of, const int* __restrict__ row_ptr,
    int* __restrict__ srev, int n, int n_pairs, int n_nodes, int bins, int chunk)
{
    int c = blockIdx.x & (C_CHUNK - 1);
    int p = blockIdx.x / C_CHUNK;
    int nlo = p * bins;
    int nhi = min(nlo + bins, n_nodes);
    int slo = row_ptr[nlo];
    int shi = row_ptr[nhi];
    int lo = c * chunk, hi = min(lo + chunk, n);
    for (int i = lo + threadIdx.x; i < hi; i += 1024) {
        int s = slot_of[i];
        if (s >= slo && s < shi) {
            int r = (i < n_pairs) ? i + n_pairs : i - n_pairs;
            srev[s] = slot_of[r];
        }
    }
}

// ---------------------------------------------------------------------------
// Fused per-node kernel (one wave per node):
//  phase 1: read node's contiguous dst-block of messages (sequential),
//           belief b = softmax(log_priors + sum log m) in-register.
//  phase 2: for each incoming slot s (edge w->u), outgoing message
//           m_out[u->w] = (sum_t + (e-1)t)/( (15+e) sum_t ), t = b/m[s],
//           scatter-written to srev[s] (random 32B row; write path coalesces).
// Lanes: j = lane&15 (state), g = lane>>4 (4 rows in flight -> 128B/step).
// ---------------------------------------------------------------------------
template <bool WRITE_MSGS, bool WRITE_B>
__global__ void fused_kernel(const __half* __restrict__ min_,
                             __half* __restrict__ mout,
                             const int* __restrict__ srev,
                             const int* __restrict__ row_ptr,
                             const float* __restrict__ log_priors,
                             float* __restrict__ beliefs_out,
                             int n_nodes)
{
    long long gid = (long long)blockIdx.x * blockDim.x + threadIdx.x;
    int node = (int)(gid >> 6);
    if (node >= n_nodes) return;
    int lane = threadIdx.x & 63;
    int j = lane & 15;
    int g = lane >> 4;   // 0..3

    int start = row_ptr[node];
    int end   = row_ptr[node + 1];

    // phase 1: log-sum of incoming messages (m >= 1/(15+e) -> log is safe)
    float acc = 0.f;
    for (int row = start + g; row < end; row += 4)
        acc += logf(__half2float(min_[(size_t)row * NSTATES + j]));
    acc += __shfl_xor(acc, 16, 64);
    acc += __shfl_xor(acc, 32, 64);

    float lb = acc + log_priors[(size_t)node * NSTATES + j];
    float mx = lb;
#pragma unroll
    for (int off = 1; off < 16; off <<= 1)
        mx = fmaxf(mx, __shfl_xor(mx, off, 64));
    float e_ = expf(lb - mx);
    float sm = e_;
#pragma unroll
    for (int off = 1; off < 16; off <<= 1)
        sm += __shfl_xor(sm, off, 64);
    float b = e_ / sm;

    if (WRITE_B && g == 0)
        beliefs_out[(size_t)node * NSTATES + j] = b;

    if (WRITE_MSGS) {
        const float EM1  = 1.7182818284590452354f;   // e - 1
        const float SUMF = 17.718281828459045235f;   // 15 + e
        for (int row = start + g; row < end; row += 4) {
            float m = __half2float(min_[(size_t)row * NSTATES + j]); // L1-hot
            float t = b / m;
            float s = t;
            s += __shfl_xor(s, 1, 64);
            s += __shfl_xor(s, 2, 64);
            s += __shfl_xor(s, 4, 64);
            s += __shfl_xor(s, 8, 64);
            float out = fmaf(EM1, t, s) * (1.0f / (SUMF * s));
            int tgt = srev[row];                   // broadcast within group
            mout[(size_t)tgt * NSTATES + j] = __float2half(out);
        }
    }
}

// ---------------------------------------------------------------------------
extern "C" void kernel_launch(void* const* d_in, const int* in_sizes, int n_in,
                              void* d_out, int out_size, void* d_ws, size_t ws_size,
                              hipStream_t stream)
{
    const float* feat = (const float*)d_in[0];
    const float* W    = (const float*)d_in[1];
    const int*   dst  = (const int*)d_in[3];

    int n_nodes = in_sizes[0] / 128;
    int n_dir   = in_sizes[2];
    int n_pairs = n_dir / 2;

    float* out         = (float*)d_out;
    float* priors_out  = out;                               // [n_nodes*16]
    float* beliefs_out = out + (size_t)n_nodes * NSTATES;   // final b_3

    size_t NN16 = (size_t)n_nodes * NSTATES;
    size_t ME   = (size_t)n_dir * NSTATES;

    // Workspace layout (224.4 MB):
    //   bufA[ME h] | bufB[ME h] | log_priors[NN16 f32] | srev[n_dir] | row_ptr
    // Aliases (dead before message writes begin):
    //   cnt,bsum -> bufA ; percount,slot_of -> bufB
    char* base = (char*)d_ws;
    __half* bufA       = (__half*)base;
    __half* bufB       = (__half*)(base + ME * sizeof(__half));
    float*  log_priors = (float*)(base + 2 * ME * sizeof(__half));
    int*    srev       = (int*)(base + 2 * ME * sizeof(__half) + NN16 * sizeof(float));
    int*    row_ptr    = srev + n_dir;                    // n_nodes+1

    int* cnt      = (int*)bufA;                           // n_nodes
    int* bsum     = cnt + n_nodes;                        // ~n_nodes/1024+1
    int* percount = (int*)bufB;                           // C_CHUNK*n_nodes
    int* slot_of  = percount + (size_t)C_CHUNK * n_nodes; // n_dir

    const int BLK = 256;
    int nb    = (n_nodes + 1023) / 1024;
    int bins  = (n_nodes + P_PART - 1) / P_PART;
    int chunk = (n_dir + C_CHUNK - 1) / C_CHUNK;
    int grid1 = (int)((NN16 + BLK - 1) / BLK);                 // 16 lanes/node
    int gridN = (n_nodes + BLK - 1) / BLK;
    int gridB = (int)(((size_t)n_nodes * 64 + BLK - 1) / BLK); // wave/node

    // --- CSR build: atomic-free (LDS histograms + scans) ---
    hist1_kernel<<<P_PART * C_CHUNK, 1024, bins * sizeof(int), stream>>>(
        dst, percount, n_dir, n_nodes, bins, chunk);
    colscan_kernel<<<gridN, BLK, 0, stream>>>(percount, cnt, n_nodes);
    scan1_kernel<<<nb, 256, 0, stream>>>(cnt, row_ptr, bsum, n_nodes);
    scan2_kernel<<<1, 64, 0, stream>>>(bsum, nb);
    scan3_kernel<<<gridN, BLK, 0, stream>>>(row_ptr, bsum, n_nodes, n_dir);
    slot3_kernel<<<P_PART * C_CHUNK, 1024, bins * sizeof(int), stream>>>(
        dst, row_ptr, percount, slot_of, n_dir, n_nodes, bins, chunk);
    srev_kernel<<<P_PART * C_CHUNK, 1024, 0, stream>>>(
        slot_of, row_ptr, srev, n_dir, n_pairs, n_nodes, bins, chunk);

    // --- priors + iter-0 message scatter into bufA ---
    priors_kernel<<<grid1, BLK, 0, stream>>>(feat, W, priors_out, log_priors,
                                             srev, row_ptr, bufA, n_nodes);

    // --- fused iterations: m_2 = f(b_1, m_1); m_3 = f(b_2, m_2); b_3 out ---
    fused_kernel<true, false><<<gridB, BLK, 0, stream>>>(
        bufA, bufB, srev, row_ptr, log_priors, nullptr, n_nodes);
    fused_kernel<true, false><<<gridB, BLK, 0, stream>>>(
        bufB, bufA, srev, row_ptr, log_priors, nullptr, n_nodes);
    fused_kernel<false, true><<<gridB, BLK, 0, stream>>>(
        bufA, nullptr, nullptr, row_ptr, log_priors, beliefs_out, n_nodes);
}